// Round 9
// baseline (91.724 us; speedup 1.0000x reference)
//
#include <hip/hip_runtime.h>

typedef unsigned short u16;
typedef __attribute__((ext_vector_type(8))) short short8;
typedef __attribute__((ext_vector_type(8))) __bf16 bf16x8;
typedef __attribute__((ext_vector_type(4))) float f32x4;
typedef __attribute__((ext_vector_type(4))) unsigned int u32x4;

#define MFMA_BF16(a, b, c) __builtin_amdgcn_mfma_f32_16x16x32_bf16((a), (b), (c), 0, 0, 0)

__device__ __forceinline__ u16 f2bf(float f) {
    unsigned u = __builtin_bit_cast(unsigned, f);
    u += 0x7FFFu + ((u >> 16) & 1u);   // round-to-nearest-even; inputs finite
    return (u16)(u >> 16);
}

// v_cvt_pk_bf16_f32: dst = {bf16(lo), bf16(hi)} packed, RNE
__device__ __forceinline__ unsigned cvt_pk_bf16(float lo, float hi) {
    unsigned r;
    asm("v_cvt_pk_bf16_f32 %0, %1, %2" : "=v"(r) : "v"(lo), "v"(hi));
    return r;
}

// raw v_exp_f32 (exp2); denormal range flushes to 0, which is what we want
__device__ __forceinline__ float fast_exp2(float x) {
    float r;
    asm("v_exp_f32 %0, %1" : "=v"(r) : "v"(x));
    return r;
}

// ---------------------------------------------------------------------------
// Projection GEMM: O[n][c] = bf16( (X[n][:] . W[c][:] + b[c]) * alpha )
// alpha_q = SCALE * log2(e) so attention softmax can use exp2 directly.
// ---------------------------------------------------------------------------
__global__ __launch_bounds__(256) void proj_gemm(
    const float* __restrict__ Xq, const float* __restrict__ Xk, const float* __restrict__ Xv,
    const float* __restrict__ Wq, const float* __restrict__ Wk, const float* __restrict__ Wv,
    const float* __restrict__ bq, const float* __restrict__ bk, const float* __restrict__ bv,
    u16* __restrict__ Oq, u16* __restrict__ Ok, u16* __restrict__ Ov)
{
    constexpr int K = 512, N = 512;
    const int z = blockIdx.z;
    const float* __restrict__ X = (z == 0) ? Xq : (z == 1) ? Xk : Xv;
    const float* __restrict__ W = (z == 0) ? Wq : (z == 1) ? Wk : Wv;
    const float* __restrict__ bias = (z == 0) ? bq : (z == 1) ? bk : bv;
    u16* __restrict__ O = (z == 0) ? Oq : (z == 1) ? Ok : Ov;
    const float alpha = (z == 0) ? 0.125f * 1.44269504088896f : 1.0f;

    __shared__ u16 lA[128 * 64];
    __shared__ u16 lB[128 * 64];

    const int tid = threadIdx.x, lane = tid & 63, w = tid >> 6;
    const int wr = w >> 1, wc = w & 1;
    const int bm = blockIdx.x, bn = blockIdx.y;
    const int r0 = tid >> 3, cc = tid & 7;

    f32x4 acc[4][4];
    for (int m = 0; m < 4; ++m)
        for (int n = 0; n < 4; ++n)
            acc[m][n] = f32x4{0.f, 0.f, 0.f, 0.f};

    for (int kt = 0; kt < K; kt += 64) {
        __syncthreads();
        for (int p = 0; p < 4; ++p) {
            int r = r0 + p * 32;
            {
                const float4* g = (const float4*)(X + (size_t)(bm * 128 + r) * K + kt + cc * 8);
                float4 f0 = g[0], f1 = g[1];
                short8 v;
                v[0] = (short)f2bf(f0.x); v[1] = (short)f2bf(f0.y);
                v[2] = (short)f2bf(f0.z); v[3] = (short)f2bf(f0.w);
                v[4] = (short)f2bf(f1.x); v[5] = (short)f2bf(f1.y);
                v[6] = (short)f2bf(f1.z); v[7] = (short)f2bf(f1.w);
                *(short8*)&lA[r * 64 + ((cc ^ (r & 7)) << 3)] = v;
            }
            {
                const float4* g = (const float4*)(W + (size_t)(bn * 128 + r) * K + kt + cc * 8);
                float4 f0 = g[0], f1 = g[1];
                short8 v;
                v[0] = (short)f2bf(f0.x); v[1] = (short)f2bf(f0.y);
                v[2] = (short)f2bf(f0.z); v[3] = (short)f2bf(f0.w);
                v[4] = (short)f2bf(f1.x); v[5] = (short)f2bf(f1.y);
                v[6] = (short)f2bf(f1.z); v[7] = (short)f2bf(f1.w);
                *(short8*)&lB[r * 64 + ((cc ^ (r & 7)) << 3)] = v;
            }
        }
        __syncthreads();
        for (int kk = 0; kk < 2; ++kk) {
            bf16x8 af[4], bfr[4];
            for (int m = 0; m < 4; ++m) {
                int row = wr * 64 + m * 16 + (lane & 15);
                af[m] = *(const bf16x8*)&lA[row * 64 + (((kk * 4 + (lane >> 4)) ^ (row & 7)) << 3)];
            }
            for (int n = 0; n < 4; ++n) {
                int row = wc * 64 + n * 16 + (lane & 15);
                bfr[n] = *(const bf16x8*)&lB[row * 64 + (((kk * 4 + (lane >> 4)) ^ (row & 7)) << 3)];
            }
            for (int m = 0; m < 4; ++m)
                for (int n = 0; n < 4; ++n)
                    acc[m][n] = MFMA_BF16(af[m], bfr[n], acc[m][n]);
        }
    }
    for (int m = 0; m < 4; ++m)
        for (int n = 0; n < 4; ++n) {
            int row = bm * 128 + wr * 64 + m * 16 + ((lane >> 4) << 2);
            int col = bn * 128 + wc * 64 + n * 16 + (lane & 15);
            float bv_ = bias[col];
            for (int i = 0; i < 4; ++i) {
                float v = (acc[m][n][i] + bv_) * alpha;
                O[(size_t)(row + i) * N + col] = f2bf(v);
            }
        }
}

// ---------------------------------------------------------------------------
// Output GEMM
// ---------------------------------------------------------------------------
__global__ __launch_bounds__(256) void out_gemm(
    const u16* __restrict__ A, const float* __restrict__ W,
    const float* __restrict__ bias, float* __restrict__ O)
{
    constexpr int K = 512, N = 512;
    __shared__ u16 lA[128 * 64];
    __shared__ u16 lB[128 * 64];

    const int tid = threadIdx.x, lane = tid & 63, w = tid >> 6;
    const int wr = w >> 1, wc = w & 1;
    const int bm = blockIdx.x, bn = blockIdx.y;
    const int r0 = tid >> 3, cc = tid & 7;

    f32x4 acc[4][4];
    for (int m = 0; m < 4; ++m)
        for (int n = 0; n < 4; ++n)
            acc[m][n] = f32x4{0.f, 0.f, 0.f, 0.f};

    for (int kt = 0; kt < K; kt += 64) {
        __syncthreads();
        for (int p = 0; p < 4; ++p) {
            int r = r0 + p * 32;
            *(short8*)&lA[r * 64 + ((cc ^ (r & 7)) << 3)] =
                *(const short8*)(A + (size_t)(bm * 128 + r) * K + kt + cc * 8);
            const float4* g = (const float4*)(W + (size_t)(bn * 128 + r) * K + kt + cc * 8);
            float4 f0 = g[0], f1 = g[1];
            short8 v;
            v[0] = (short)f2bf(f0.x); v[1] = (short)f2bf(f0.y);
            v[2] = (short)f2bf(f0.z); v[3] = (short)f2bf(f0.w);
            v[4] = (short)f2bf(f1.x); v[5] = (short)f2bf(f1.y);
            v[6] = (short)f2bf(f1.z); v[7] = (short)f2bf(f1.w);
            *(short8*)&lB[r * 64 + ((cc ^ (r & 7)) << 3)] = v;
        }
        __syncthreads();
        for (int kk = 0; kk < 2; ++kk) {
            bf16x8 af[4], bfr[4];
            for (int m = 0; m < 4; ++m) {
                int row = wr * 64 + m * 16 + (lane & 15);
                af[m] = *(const bf16x8*)&lA[row * 64 + (((kk * 4 + (lane >> 4)) ^ (row & 7)) << 3)];
            }
            for (int n = 0; n < 4; ++n) {
                int row = wc * 64 + n * 16 + (lane & 15);
                bfr[n] = *(const bf16x8*)&lB[row * 64 + (((kk * 4 + (lane >> 4)) ^ (row & 7)) << 3)];
            }
            for (int m = 0; m < 4; ++m)
                for (int n = 0; n < 4; ++n)
                    acc[m][n] = MFMA_BF16(af[m], bfr[n], acc[m][n]);
        }
    }
    for (int m = 0; m < 4; ++m)
        for (int n = 0; n < 4; ++n) {
            int row = bm * 128 + wr * 64 + m * 16 + ((lane >> 4) << 2);
            int col = bn * 128 + wc * 64 + n * 16 + (lane & 15);
            float bv_ = bias[col];
            for (int i = 0; i < 4; ++i)
                O[(size_t)(row + i) * N + col] = acc[m][n][i] + bv_;
        }
}

// ---------------------------------------------------------------------------
// Flash attention v7: 32 q-rows PER WAVE (two register Q-sets A/B) so every
// K/V LDS fragment read feeds TWO MFMAs (halves LDS-pipe load, the measured
// bottleneck). Block = 256 threads / 4 waves = 2 KV-split groups x 2 waves.
// V staged via coalesced 4-row loads + ds_write_b64 quads (conflict-free
// under sw(d)); K via 4x b128. Exact flash-merge of the two groups at end.
// ---------------------------------------------------------------------------
__global__ __launch_bounds__(256) void attn_k(
    const u16* __restrict__ Qp, const u16* __restrict__ Kp, const u16* __restrict__ Vp,
    const unsigned char* __restrict__ mask, u16* __restrict__ Ob)
{
    constexpr int C = 512, NK = 2048, KVH = 1024, NTG = KVH / 64;   // 16 tiles/group
    __shared__ u16 lK[2][64 * 64];
    __shared__ u16 lV[2][64 * 64];

    const int tid = threadIdx.x, lane = tid & 63, w = tid >> 6;
    const int g = w >> 1, wg = w & 1;
    const int gd = lane >> 4, q15 = lane & 15;
    const int bh = blockIdx.x, qb = blockIdx.y;
    const int b = bh >> 3, h = bh & 7;
    const size_t qrow0 = (size_t)b * 2048 + qb * 64;
    const size_t krow0 = (size_t)b * 2048 + (size_t)g * KVH;
    const int col0 = h * 64;
    const int gt = tid & 127;          // thread index within group (128 threads)
    const int rs8 = gt >> 3, cc = gt & 7;

    // Q register sets: set A = rows wg*32 + q15, set B = rows wg*32 + 16 + q15
    bf16x8 qfA[2], qfB[2];
    {
        const u16* qa = Qp + (qrow0 + wg * 32 + q15) * C + col0;
        qfA[0] = *(const bf16x8*)(qa + gd * 8);
        qfA[1] = *(const bf16x8*)(qa + 32 + gd * 8);
        const u16* qbp = qa + 16 * C;
        qfB[0] = *(const bf16x8*)(qbp + gd * 8);
        qfB[1] = *(const bf16x8*)(qbp + 32 + gd * 8);
    }

    float mstA = -1e30f, lstA = 0.f, mstB = -1e30f, lstB = 0.f;
    f32x4 oaccA[4], oaccB[4];
    #pragma unroll
    for (int i = 0; i < 4; ++i) {
        oaccA[i] = f32x4{0.f, 0.f, 0.f, 0.f};
        oaccB[i] = f32x4{0.f, 0.f, 0.f, 0.f};
    }

    // prefetch tile 0 for OWN group: K rows rs8+p*16 (coalesced), V rows 4*rs8+j (coalesced)
    short8 kpre[4], vpre[4];
    #pragma unroll
    for (int p = 0; p < 4; ++p)
        kpre[p] = *(const short8*)(Kp + (krow0 + rs8 + p * 16) * C + col0 + cc * 8);
    #pragma unroll
    for (int j = 0; j < 4; ++j)
        vpre[j] = *(const short8*)(Vp + (krow0 + 4 * rs8 + j) * C + col0 + cc * 8);

    for (int t = 0; t < NTG; ++t) {
        __syncthreads();   // previous compute done; safe to overwrite LDS
        // K: 4 x ds_write_b128, swizzled rows
        #pragma unroll
        for (int p = 0; p < 4; ++p) {
            int r = rs8 + p * 16;
            *(short8*)&lK[g][r * 64 + ((cc ^ (r & 7)) << 3)] = kpre[p];
        }
        // V^T: 8 x ds_write_b64 quads: V[4*rs8 .. +3][d] for d = cc*8+jj
        #pragma unroll
        for (int jj = 0; jj < 8; ++jj) {
            int d = cc * 8 + jj;
            int swd = (d + (d >> 3)) & 7;
            unsigned w0 = ((unsigned)(u16)vpre[0][jj]) | (((unsigned)(u16)vpre[1][jj]) << 16);
            unsigned w1 = ((unsigned)(u16)vpre[2][jj]) | (((unsigned)(u16)vpre[3][jj]) << 16);
            uint2 pr; pr.x = w0; pr.y = w1;
            *(uint2*)&lV[g][d * 64 + (((rs8 >> 1) ^ swd) << 3) + 4 * (rs8 & 1)] = pr;
        }
        // issue next-tile prefetch (lands during compute below)
        if (t + 1 < NTG) {
            #pragma unroll
            for (int p = 0; p < 4; ++p)
                kpre[p] = *(const short8*)(Kp + (krow0 + (t + 1) * 64 + rs8 + p * 16) * C + col0 + cc * 8);
            #pragma unroll
            for (int j = 0; j < 4; ++j)
                vpre[j] = *(const short8*)(Vp + (krow0 + (t + 1) * 64 + 4 * rs8 + j) * C + col0 + cc * 8);
        }
        __syncthreads();   // staging visible

        unsigned char mby = mask[(size_t)b * NK + g * KVH + t * 64 + lane];

        // QK^T: each K fragment feeds BOTH q-sets
        f32x4 sA[4], sB[4];
        #pragma unroll
        for (int i = 0; i < 4; ++i) {
            sA[i] = f32x4{0.f, 0.f, 0.f, 0.f};
            sB[i] = f32x4{0.f, 0.f, 0.f, 0.f};
        }
        const u16* Kc = &lK[g][0];
        __builtin_amdgcn_s_setprio(1);
        #pragma unroll
        for (int kb = 0; kb < 2; ++kb)
            #pragma unroll
            for (int t4 = 0; t4 < 4; ++t4) {
                int krow = t4 * 16 + q15;
                bf16x8 kf = *(const bf16x8*)&Kc[krow * 64 + (((kb * 4 + gd) ^ (krow & 7)) << 3)];
                sA[t4] = MFMA_BF16(kf, qfA[kb], sA[t4]);
                sB[t4] = MFMA_BF16(kf, qfB[kb], sB[t4]);
            }
        __builtin_amdgcn_s_setprio(0);

        // key-padding mask (uniform branch; all-false for this input)
        unsigned long long m64 = __ballot(mby != 0);
        if (m64) {
            #pragma unroll
            for (int t4 = 0; t4 < 4; ++t4)
                #pragma unroll
                for (int i = 0; i < 4; ++i) {
                    int k = t4 * 16 + gd * 4 + i;
                    if ((m64 >> k) & 1ull) { sA[t4][i] = -1e30f; sB[t4][i] = -1e30f; }
                }
        }

        // ---- softmax set A ----
        bf16x8 paA[2], paB[2];
        {
            float pmax = sA[0][0];
            #pragma unroll
            for (int t4 = 0; t4 < 4; ++t4)
                #pragma unroll
                for (int i = 0; i < 4; ++i) pmax = fmaxf(pmax, sA[t4][i]);
            if (!__all(pmax - mstA <= 11.0f)) {
                float rm = fmaxf(pmax, __shfl_xor(pmax, 16));
                rm = fmaxf(rm, __shfl_xor(rm, 32));
                float mn = fmaxf(mstA, rm);
                float sf = exp2f(mstA - mn);
                mstA = mn; lstA *= sf;
                #pragma unroll
                for (int i = 0; i < 4; ++i) {
                    float sfi = __shfl(sf, (lane & 48) | ((gd << 2) + i));
                    #pragma unroll
                    for (int t2 = 0; t2 < 4; ++t2) oaccA[t2][i] *= sfi;
                }
            }
            float rsum = 0.f;
            #pragma unroll
            for (int kb = 0; kb < 2; ++kb) {
                float ea[4], eb[4];
                #pragma unroll
                for (int i = 0; i < 4; ++i) {
                    ea[i] = fast_exp2(sA[2 * kb][i] - mstA);
                    eb[i] = fast_exp2(sA[2 * kb + 1][i] - mstA);
                    rsum += ea[i] + eb[i];
                }
                u32x4 pw;
                pw[0] = cvt_pk_bf16(ea[0], ea[1]);
                pw[1] = cvt_pk_bf16(ea[2], ea[3]);
                pw[2] = cvt_pk_bf16(eb[0], eb[1]);
                pw[3] = cvt_pk_bf16(eb[2], eb[3]);
                paA[kb] = __builtin_bit_cast(bf16x8, pw);
            }
            lstA += rsum;
        }
        // ---- softmax set B ----
        {
            float pmax = sB[0][0];
            #pragma unroll
            for (int t4 = 0; t4 < 4; ++t4)
                #pragma unroll
                for (int i = 0; i < 4; ++i) pmax = fmaxf(pmax, sB[t4][i]);
            if (!__all(pmax - mstB <= 11.0f)) {
                float rm = fmaxf(pmax, __shfl_xor(pmax, 16));
                rm = fmaxf(rm, __shfl_xor(rm, 32));
                float mn = fmaxf(mstB, rm);
                float sf = exp2f(mstB - mn);
                mstB = mn; lstB *= sf;
                #pragma unroll
                for (int i = 0; i < 4; ++i) {
                    float sfi = __shfl(sf, (lane & 48) | ((gd << 2) + i));
                    #pragma unroll
                    for (int t2 = 0; t2 < 4; ++t2) oaccB[t2][i] *= sfi;
                }
            }
            float rsum = 0.f;
            #pragma unroll
            for (int kb = 0; kb < 2; ++kb) {
                float ea[4], eb[4];
                #pragma unroll
                for (int i = 0; i < 4; ++i) {
                    ea[i] = fast_exp2(sB[2 * kb][i] - mstB);
                    eb[i] = fast_exp2(sB[2 * kb + 1][i] - mstB);
                    rsum += ea[i] + eb[i];
                }
                u32x4 pw;
                pw[0] = cvt_pk_bf16(ea[0], ea[1]);
                pw[1] = cvt_pk_bf16(ea[2], ea[3]);
                pw[2] = cvt_pk_bf16(eb[0], eb[1]);
                pw[3] = cvt_pk_bf16(eb[2], eb[3]);
                paB[kb] = __builtin_bit_cast(bf16x8, pw);
            }
            lstB += rsum;
        }

        // PV: each V fragment feeds BOTH q-sets (k-slot remap, no shuffles)
        const u16* Vc = &lV[g][0];
        __builtin_amdgcn_s_setprio(1);
        #pragma unroll
        for (int kb = 0; kb < 2; ++kb)
            #pragma unroll
            for (int t2 = 0; t2 < 4; ++t2) {
                int d = t2 * 16 + q15;
                int swd = (d + (d >> 3)) & 7;
                int base = d * 64 + 4 * (gd & 1);
                uint2 v0 = *(const uint2*)&Vc[base + (((4 * kb + 0 + (gd >> 1)) ^ swd) << 3)];
                uint2 v1 = *(const uint2*)&Vc[base + (((4 * kb + 2 + (gd >> 1)) ^ swd) << 3)];
                u32x4 vw; vw[0] = v0.x; vw[1] = v0.y; vw[2] = v1.x; vw[3] = v1.y;
                bf16x8 vf = __builtin_bit_cast(bf16x8, vw);
                oaccA[t2] = MFMA_BF16(paA[kb], vf, oaccA[t2]);
                oaccB[t2] = MFMA_BF16(paB[kb], vf, oaccB[t2]);
            }
        __builtin_amdgcn_s_setprio(0);
    }

    // row-reduce partial sums (lanes sharing q15 across gd)
    float lsA = lstA + __shfl_xor(lstA, 16); lsA += __shfl_xor(lsA, 32);
    float lsB = lstB + __shfl_xor(lstB, 16); lsB += __shfl_xor(lsB, 32);

    __syncthreads();   // all compute done before overlaying LDS

    // merge the two groups through LDS: 4 records/lane-slot x 18 floats = 18 KB
    float* mrg = (float*)&lK[0][0];
    const int recA = ((wg * 2 + 0) * 64 + lane) * 18;
    const int recB = ((wg * 2 + 1) * 64 + lane) * 18;
    if (g == 1) {
        #pragma unroll
        for (int t2 = 0; t2 < 4; ++t2)
            #pragma unroll
            for (int i = 0; i < 4; ++i) {
                mrg[recA + t2 * 4 + i] = oaccA[t2][i];
                mrg[recB + t2 * 4 + i] = oaccB[t2][i];
            }
        mrg[recA + 16] = mstA; mrg[recA + 17] = lsA;
        mrg[recB + 16] = mstB; mrg[recB + 17] = lsB;
    }
    __syncthreads();
    if (g == 0) {
        // set A
        {
            float m1 = mrg[recA + 16], l1 = mrg[recA + 17];
            float m = fmaxf(mstA, m1);
            float a0 = exp2f(mstA - m), a1 = exp2f(m1 - m);
            float lr = lsA * a0 + l1 * a1;
            #pragma unroll
            for (int i = 0; i < 4; ++i) {
                int srcl = (lane & 48) | ((gd << 2) + i);
                float a0i = __shfl(a0, srcl), a1i = __shfl(a1, srcl), li = __shfl(lr, srcl);
                float inv = 1.f / li;
                int qg = qb * 64 + wg * 32 + gd * 4 + i;
                #pragma unroll
                for (int t2 = 0; t2 < 4; ++t2) {
                    float o1 = mrg[recA + t2 * 4 + i];
                    float vfin = (oaccA[t2][i] * a0i + o1 * a1i) * inv;
                    Ob[((size_t)b * 2048 + qg) * C + col0 + t2 * 16 + q15] = f2bf(vfin);
                }
            }
        }
        // set B
        {
            float m1 = mrg[recB + 16], l1 = mrg[recB + 17];
            float m = fmaxf(mstB, m1);
            float a0 = exp2f(mstB - m), a1 = exp2f(m1 - m);
            float lr = lsB * a0 + l1 * a1;
            #pragma unroll
            for (int i = 0; i < 4; ++i) {
                int srcl = (lane & 48) | ((gd << 2) + i);
                float a0i = __shfl(a0, srcl), a1i = __shfl(a1, srcl), li = __shfl(lr, srcl);
                float inv = 1.f / li;
                int qg = qb * 64 + wg * 32 + 16 + gd * 4 + i;
                #pragma unroll
                for (int t2 = 0; t2 < 4; ++t2) {
                    float o1 = mrg[recB + t2 * 4 + i];
                    float vfin = (oaccB[t2][i] * a0i + o1 * a1i) * inv;
                    Ob[((size_t)b * 2048 + qg) * C + col0 + t2 * 16 + q15] = f2bf(vfin);
                }
            }
        }
    }
}

extern "C" void kernel_launch(void* const* d_in, const int* in_sizes, int n_in,
                              void* d_out, int out_size, void* d_ws, size_t ws_size,
                              hipStream_t stream) {
    const float* query = (const float*)d_in[0];
    const float* key   = (const float*)d_in[1];
    const float* value = (const float*)d_in[2];
    const unsigned char* mask = (const unsigned char*)d_in[3];
    const float* Wq = (const float*)d_in[4];
    const float* bq = (const float*)d_in[5];
    const float* Wk = (const float*)d_in[6];
    const float* bk = (const float*)d_in[7];
    const float* Wv = (const float*)d_in[8];
    const float* bv = (const float*)d_in[9];
    const float* Wo = (const float*)d_in[10];
    const float* bo = (const float*)d_in[11];

    u16* ws = (u16*)d_ws;
    u16* Qp = ws;
    u16* Kp = ws + 2097152;
    u16* Vp = ws + 4194304;
    u16* Ob = ws + 6291456;

    dim3 gp(32, 4, 3);
    proj_gemm<<<gp, 256, 0, stream>>>(query, key, value, Wq, Wk, Wv, bq, bk, bv, Qp, Kp, Vp);

    dim3 ga(16, 32);   // x = bh (XCD locality for K/V), y = q-tile
    attn_k<<<ga, 256, 0, stream>>>(Qp, Kp, Vp, mask, Ob);

    dim3 go(32, 4);
    out_gemm<<<go, 256, 0, stream>>>(Ob, Wo, bo, (float*)d_out);
}